// Round 16
// baseline (137.797 us; speedup 1.0000x reference)
//
#include <hip/hip_runtime.h>
#include <hip/hip_bf16.h>
#include <hip/hip_fp16.h>

// ScaledDotProductAttention N=M=8192, DK=DV=256, fp32 io.
// R16 = R15 (cross-tile QKT||PV interleave, P carried in regs) with DUAL
// QKT chains (sA/sB, as verified in R9) inside the interleaved body:
//   (sA=MFMA(K,Q), PV(pa0,vt))x8 ; (sB=MFMA(K,Q), PV(pa1,vt))x8
// so the s-dependency chain never gates the MFMA stream. Rest identical.

typedef __attribute__((ext_vector_type(16))) float floatx16;
typedef __attribute__((ext_vector_type(8)))  short short8;

union S8u { short8 v; unsigned short u[8]; };

#if __has_builtin(__builtin_amdgcn_exp2f)
#define EXP2F(x) __builtin_amdgcn_exp2f(x)
#else
#define EXP2F(x) exp2f(x)
#endif

__device__ __forceinline__ unsigned short f2bf(float f) {
    unsigned int u = __builtin_bit_cast(unsigned int, f);
    unsigned int r = u + 0x7fffu + ((u >> 16) & 1u);   // RNE
    return (unsigned short)(r >> 16);
}

__device__ __forceinline__ unsigned cvtpk_bf16(float lo, float hi) {
    unsigned r;
    asm("v_cvt_pk_bf16_f32 %0, %1, %2" : "=v"(r) : "v"(lo), "v"(hi));
    return r;
}

__device__ __forceinline__ void gload16(const void* g, void* l) {
    __builtin_amdgcn_global_load_lds(
        (const __attribute__((address_space(1))) unsigned int*)g,
        (__attribute__((address_space(3))) unsigned int*)l, 16, 0, 0);
}

// ---------------- fused prep kernel: V transpose + K cvt ----------------

__global__ void prep_kernel(const float* __restrict__ K,
                            const float* __restrict__ V,
                            unsigned short* __restrict__ Kb,
                            unsigned short* __restrict__ Vt) {
    __shared__ unsigned short T[64][72];
    const int kv0 = blockIdx.x * 64;
    const int v0  = blockIdx.y * 64;
    const int tid = threadIdx.x;           // 256
#pragma unroll
    for (int it = 0; it < 4; ++it) {
        int flat = it * 256 + tid;
        int r  = flat >> 4;
        int c4 = (flat & 15) * 4;
        float4 f = *reinterpret_cast<const float4*>(
            V + (size_t)(kv0 + r) * 256 + v0 + c4);
        T[c4 + 0][r] = f2bf(f.x);
        T[c4 + 1][r] = f2bf(f.y);
        T[c4 + 2][r] = f2bf(f.z);
        T[c4 + 3][r] = f2bf(f.w);
    }
    __syncthreads();
#pragma unroll
    for (int it = 0; it < 2; ++it) {
        int flat = it * 256 + tid;
        int r  = flat >> 3;
        int c8 = (flat & 7) * 8;
        short8 v8 = *reinterpret_cast<const short8*>(&T[r][c8]);
        *reinterpret_cast<short8*>(Vt + (size_t)(v0 + r) * 8192 + kv0 + c8) = v8;
    }
    // ---- K conversion slice: 512 chunks-of-8 per block ----
    const int bid = blockIdx.x + 128 * blockIdx.y;   // 0..511
#pragma unroll
    for (int it = 0; it < 2; ++it) {
        int i = bid * 512 + it * 256 + tid;          // 0..262143
        const float4* p = reinterpret_cast<const float4*>(K) + (size_t)i * 2;
        float4 a = p[0], b = p[1];
        S8u r;
        r.u[0] = f2bf(a.x); r.u[1] = f2bf(a.y);
        r.u[2] = f2bf(a.z); r.u[3] = f2bf(a.w);
        r.u[4] = f2bf(b.x); r.u[5] = f2bf(b.y);
        r.u[6] = f2bf(b.z); r.u[7] = f2bf(b.w);
        *reinterpret_cast<short8*>(Kb + (size_t)i * 8) = r.v;
    }
}

// ---------------- main attention kernel ----------------

#define MFMA_B16 __builtin_amdgcn_mfma_f32_32x32x16_bf16

__global__ __launch_bounds__(256, 2)
void attn_kernel(const float* __restrict__ Qf,            // [8192][256] fp32
                 const unsigned short* __restrict__ Kb,   // [8192][256] bf16
                 const unsigned short* __restrict__ VtG,  // [256][8192] bf16
                 __half* __restrict__ Opart,              // [NG][8192][256]
                 float* __restrict__ Ml,                  // [NG][8192][2]
                 int kv_span, int gshift) {
    // [buf][ K 16KB ] and [buf][ Vt 16KB ]  (tile = 32 kv)
    __shared__ __align__(16) unsigned char kbuf[2][16384];
    __shared__ __align__(16) unsigned char vbuf[2][16384];

    const int tid  = threadIdx.x;
    const int lane = tid & 63;
    const int w    = tid >> 6;     // 0..3
    const int l31  = lane & 31;
    const int h    = lane >> 5;    // 0/1

    const int ngm1 = (1 << gshift) - 1;
    const int id   = blockIdx.x + 64 * blockIdx.y;
    const int g    = id & ngm1;          // XCD-affine
    const int qblk = id >> gshift;       // 0..63
    const int kv_begin = g * kv_span;
    const int tiles = kv_span >> 5;
    const int q0 = qblk * 128 + w * 32;

    // Q as B-fragments, fp32 -> bf16 with scale log2(e)/16 (exp2 domain)
    const float qs = 0.09016844005556021f;
    short8 qf[16];
    {
        const float* qp = Qf + (size_t)(q0 + l31) * 256 + h * 8;
#pragma unroll
        for (int ds = 0; ds < 16; ++ds) {
            float4 f0 = *reinterpret_cast<const float4*>(qp + ds * 16);
            float4 f1 = *reinterpret_cast<const float4*>(qp + ds * 16 + 4);
            uint4 uu;
            uu.x = cvtpk_bf16(f0.x * qs, f0.y * qs);
            uu.y = cvtpk_bf16(f0.z * qs, f0.w * qs);
            uu.z = cvtpk_bf16(f1.x * qs, f1.y * qs);
            uu.w = cvtpk_bf16(f1.z * qs, f1.w * qs);
            qf[ds] = __builtin_bit_cast(short8, uu);
        }
    }

    floatx16 o[8];
#pragma unroll
    for (int vt = 0; vt < 8; ++vt)
#pragma unroll
        for (int r = 0; r < 16; ++r) o[vt][r] = 0.f;
    float m_run = -1e30f, l_run = 0.f;

    // staging offsets (verified R9 maps): 16B-chunk j = i*256 + tid
    int offk[4], offv[4];
#pragma unroll
    for (int i = 0; i < 4; ++i) {
        int j  = i * 256 + tid;
        int rk = j >> 5, ck = (j & 31) ^ (rk & 7);
        offk[i] = rk * 256 + ck * 8;
        int rv = j >> 2, cv = (j & 3) ^ ((rv >> 1) & 3);
        offv[i] = rv * 8192 + cv * 8;
    }

    auto STAGEK = [&](int kv0, int bufsel) {
        const unsigned short* ks = Kb + (size_t)kv0 * 256;
#pragma unroll
        for (int i = 0; i < 4; ++i)
            gload16(ks + offk[i], &kbuf[bufsel][(i * 256 + w * 64) * 16]);
    };
    auto STAGEV = [&](int kv0, int bufsel) {
        const unsigned short* vs = VtG + kv0;
#pragma unroll
        for (int i = 0; i < 4; ++i)
            gload16(vs + offv[i], &vbuf[bufsel][(i * 256 + w * 64) * 16]);
    };

    // ---- prologue: K(0); V(0) into BOTH buffers (body-0 dummy PV reads
    // vbuf[1] with pa=0 -> real finite data, contributes exactly 0) ----
    STAGEK(kv_begin, 0);
    STAGEV(kv_begin, 0);
    STAGEV(kv_begin, 1);
    __syncthreads();

    const int swz  = l31 & 7;          // K-read swizzle
    const int vswz = (l31 >> 1) & 3;   // V-read swizzle

    auto buildPA = [&](const floatx16& sv, int rbase) -> short8 {
        unsigned cpk0 = cvtpk_bf16(sv[rbase + 0], sv[rbase + 1]);
        unsigned cpk1 = cvtpk_bf16(sv[rbase + 2], sv[rbase + 3]);
        unsigned cpk2 = cvtpk_bf16(sv[rbase + 4], sv[rbase + 5]);
        unsigned cpk3 = cvtpk_bf16(sv[rbase + 6], sv[rbase + 7]);
        uint4 uu;
#if __has_builtin(__builtin_amdgcn_permlane32_swap)
        auto r02 = __builtin_amdgcn_permlane32_swap((int)cpk0, (int)cpk2, false, false);
        auto r13 = __builtin_amdgcn_permlane32_swap((int)cpk1, (int)cpk3, false, false);
        uu.x = (unsigned)r02[0]; uu.y = (unsigned)r13[0];
        uu.z = (unsigned)r02[1]; uu.w = (unsigned)r13[1];
#else
        unsigned send0 = h ? cpk0 : cpk2;
        unsigned send1 = h ? cpk1 : cpk3;
        unsigned r0 = (unsigned)__shfl_xor((int)send0, 32);
        unsigned r1 = (unsigned)__shfl_xor((int)send1, 32);
        uu.x = h ? r0 : cpk0;
        uu.y = h ? r1 : cpk1;
        uu.z = h ? cpk2 : r0;
        uu.w = h ? cpk3 : r1;
#endif
        return __builtin_bit_cast(short8, uu);
    };

    // P(t-1) carried across bodies (zero for body 0 -> dummy PV adds 0)
    short8 pa0 = __builtin_bit_cast(short8, uint4{0u, 0u, 0u, 0u});
    short8 pa1 = pa0;

    for (int t = 0; t < tiles; ++t) {
        const int cur = t & 1;
        const int nxt = cur ^ 1;
        const int tn  = (t + 1 < tiles) ? t + 1 : t;   // dummy restage on last

        // ---- issue staging: K(t+1) and V(t); land by end of body ----
        STAGEK(kv_begin + tn * 32, nxt);
        STAGEV(kv_begin + t * 32, cur);

        const unsigned char* kl  = kbuf[cur];   // K(t)
        const unsigned char* vlp = vbuf[nxt];   // V(t-1)  ((t-1)&1 == nxt)

        // ---- dual-chain QKT(t) interleaved 1:1 with PV(t-1) ----
        floatx16 sA, sB;
#pragma unroll
        for (int r = 0; r < 16; ++r) { sA[r] = 0.f; sB[r] = 0.f; }
        __builtin_amdgcn_s_setprio(1);
#pragma unroll
        for (int ds = 0; ds < 8; ++ds) {
            int c0 = (ds * 2 + h) ^ swz;
            short8 a0 = *reinterpret_cast<const short8*>(
                kl + (size_t)l31 * 512 + c0 * 16);
            sA = MFMA_B16(a0, qf[ds], sA, 0, 0, 0);
            int cvs = h ^ vswz;
            short8 b = *reinterpret_cast<const short8*>(
                vlp + (size_t)(ds * 32 + l31) * 64 + cvs * 16);
            o[ds] = MFMA_B16(pa0, b, o[ds], 0, 0, 0);
        }
#pragma unroll
        for (int ds = 8; ds < 16; ++ds) {
            int c0 = (ds * 2 + h) ^ swz;
            short8 a0 = *reinterpret_cast<const short8*>(
                kl + (size_t)l31 * 512 + c0 * 16);
            sB = MFMA_B16(a0, qf[ds], sB, 0, 0, 0);
            int cvs = (2 + h) ^ vswz;
            short8 b = *reinterpret_cast<const short8*>(
                vlp + (size_t)((ds - 8) * 32 + l31) * 64 + cvs * 16);
            o[ds - 8] = MFMA_B16(pa1, b, o[ds - 8], 0, 0, 0);
        }
        __builtin_amdgcn_s_setprio(0);
        floatx16 s;
#pragma unroll
        for (int r = 0; r < 16; ++r) s[r] = sA[r] + sB[r];

        // ---- online softmax on tile t (exp2 domain, tree reductions) ----
        {
            float t4[4];
#pragma unroll
            for (int i = 0; i < 4; ++i)
                t4[i] = fmaxf(fmaxf(s[i], s[i + 4]),
                              fmaxf(s[i + 8], s[i + 12]));
            float mt = fmaxf(fmaxf(t4[0], t4[1]), fmaxf(t4[2], t4[3]));
            mt = fmaxf(mt, __shfl_xor(mt, 32));
            if (__any(mt > m_run + 11.5f)) {      // defer-max (log2 units)
                float mnew = fmaxf(m_run, mt);
                float al = EXP2F(m_run - mnew);
                m_run = mnew;
                l_run *= al;
#pragma unroll
                for (int reg = 0; reg < 16; ++reg) {
                    int srcl = ((reg & 3) + 8 * (reg >> 2)) + 4 * h;
                    float alr = __shfl(al, srcl);
#pragma unroll
                    for (int vt = 0; vt < 8; ++vt) o[vt][reg] *= alr;
                }
            }
#pragma unroll
            for (int r = 0; r < 16; ++r) s[r] = EXP2F(s[r] - m_run);
            float u[4];
#pragma unroll
            for (int i = 0; i < 4; ++i)
                u[i] = (s[i] + s[i + 4]) + (s[i + 8] + s[i + 12]);
            float lt = (u[0] + u[1]) + (u[2] + u[3]);
            lt += __shfl_xor(lt, 32);
            l_run += lt;
        }
        pa0 = buildPA(s, 0);
        pa1 = buildPA(s, 8);

        // ---- drain this body's staging; rotate ----
        __syncthreads();
    }

    // ---- epilogue PV for the last tile ----
    {
        const unsigned char* vlq = vbuf[(tiles - 1) & 1];
        __builtin_amdgcn_s_setprio(1);
#pragma unroll
        for (int kk = 0; kk < 2; ++kk) {
            int cvs = (kk * 2 + h) ^ vswz;
#pragma unroll
            for (int vt = 0; vt < 8; ++vt) {
                short8 b = *reinterpret_cast<const short8*>(
                    vlq + (size_t)(vt * 32 + l31) * 64 + cvs * 16);
                o[vt] = MFMA_B16(kk ? pa1 : pa0, b, o[vt], 0, 0, 0);
            }
        }
        __builtin_amdgcn_s_setprio(0);
    }

    // ---- epilogue: normalized fp16 partial + (m,l) fp32 ----
    const size_t gq = (size_t)g * 8192;
    float linv = 1.0f / l_run;
#pragma unroll
    for (int reg = 0; reg < 16; ++reg) {
        int row = (reg & 3) + 8 * (reg >> 2) + 4 * h;
        float li = __shfl(linv, row);
#pragma unroll
        for (int vt = 0; vt < 8; ++vt)
            Opart[(gq + q0 + row) * 256 + vt * 32 + l31] =
                __float2half_rn(o[vt][reg] * li);
    }
    if (h == 0) {
        size_t idx = (gq + q0 + l31) * 2;
        Ml[idx]     = m_run;   // log2 domain
        Ml[idx + 1] = l_run;
    }
}

// ---------------- merge kernel (half2-vectorized) ----------------

__global__ void merge_kernel(const __half* __restrict__ Opart,
                             const float* __restrict__ Ml,
                             float* __restrict__ out, int ngroups) {
    const int row = blockIdx.x;
    const int c2  = threadIdx.x;           // 0..127, col pair
    float m = -1e30f;
    for (int g = 0; g < ngroups; ++g)
        m = fmaxf(m, Ml[((size_t)g * 8192 + row) * 2]);
    float den = 0.f, ax = 0.f, ay = 0.f;
    for (int g = 0; g < ngroups; ++g) {
        float wg = EXP2F(Ml[((size_t)g * 8192 + row) * 2] - m) *
                   Ml[((size_t)g * 8192 + row) * 2 + 1];
        den += wg;
        __half2 h2 = *reinterpret_cast<const __half2*>(
            &Opart[((size_t)g * 8192 + row) * 256 + c2 * 2]);
        float2 f = __half22float2(h2);
        ax += wg * f.x;
        ay += wg * f.y;
    }
    float dinv = 1.0f / den;
    float2 r; r.x = ax * dinv; r.y = ay * dinv;
    *reinterpret_cast<float2*>(&out[(size_t)row * 256 + c2 * 2]) = r;
}

// ---------------- launcher ----------------

extern "C" void kernel_launch(void* const* d_in, const int* in_sizes, int n_in,
                              void* d_out, int out_size, void* d_ws, size_t ws_size,
                              hipStream_t stream) {
    const float* Q = (const float*)d_in[0];
    const float* K = (const float*)d_in[1];
    const float* V = (const float*)d_in[2];
    float* out = (float*)d_out;

    unsigned short* Kb = (unsigned short*)d_ws;            // 4 MiB
    unsigned short* Vt = Kb + (size_t)8192 * 256;          // 4 MiB

    const size_t base = (size_t)8192 * 256 * 2 * 2;        // 8 MiB
    const size_t osz  = (size_t)8192 * 256 * 2;            // 4 MiB/group (fp16)
    const size_t mlsz = (size_t)8192 * 2 * 4;              // 64 KiB/group

    int gshift = 3;
    for (; gshift > 0; --gshift)
        if (base + ((osz + mlsz) << gshift) <= ws_size) break;
    int ng = 1 << gshift;

    __half* Opart = (__half*)((char*)d_ws + base);
    float*  Mlp   = (float*)((char*)d_ws + base + osz * (size_t)ng);

    prep_kernel<<<dim3(128, 4), 256, 0, stream>>>(K, V, Kb, Vt);
    attn_kernel<<<dim3(64, ng), 256, 0, stream>>>(Q, Kb, Vt, Opart, Mlp,
                                                  8192 / ng, gshift);
    merge_kernel<<<8192, 128, 0, stream>>>(Opart, Mlp, out, ng);
}

// Round 17
// 119.694 us; speedup vs baseline: 1.1512x; 1.1512x over previous
//
#include <hip/hip_runtime.h>
#include <hip/hip_bf16.h>
#include <hip/hip_fp16.h>

// ScaledDotProductAttention N=M=8192, DK=DV=256, fp32 io.
// R17 = R15 verbatim (best verified: 122.6us total, attn ~115us).
// Cross-tile MFMA pairing: P(t-1) held in registers (bf16 pa-frags);
// body t runs QKT(t) interleaved 1:1 with PV(t-1), then SM(t).
// 2 blocks/CU, KV tile 32, one __syncthreads per body.

typedef __attribute__((ext_vector_type(16))) float floatx16;
typedef __attribute__((ext_vector_type(8)))  short short8;

union S8u { short8 v; unsigned short u[8]; };

#if __has_builtin(__builtin_amdgcn_exp2f)
#define EXP2F(x) __builtin_amdgcn_exp2f(x)
#else
#define EXP2F(x) exp2f(x)
#endif

__device__ __forceinline__ unsigned short f2bf(float f) {
    unsigned int u = __builtin_bit_cast(unsigned int, f);
    unsigned int r = u + 0x7fffu + ((u >> 16) & 1u);   // RNE
    return (unsigned short)(r >> 16);
}

__device__ __forceinline__ unsigned cvtpk_bf16(float lo, float hi) {
    unsigned r;
    asm("v_cvt_pk_bf16_f32 %0, %1, %2" : "=v"(r) : "v"(lo), "v"(hi));
    return r;
}

__device__ __forceinline__ void gload16(const void* g, void* l) {
    __builtin_amdgcn_global_load_lds(
        (const __attribute__((address_space(1))) unsigned int*)g,
        (__attribute__((address_space(3))) unsigned int*)l, 16, 0, 0);
}

// ---------------- fused prep kernel: V transpose + K cvt ----------------

__global__ void prep_kernel(const float* __restrict__ K,
                            const float* __restrict__ V,
                            unsigned short* __restrict__ Kb,
                            unsigned short* __restrict__ Vt) {
    __shared__ unsigned short T[64][72];
    const int kv0 = blockIdx.x * 64;
    const int v0  = blockIdx.y * 64;
    const int tid = threadIdx.x;           // 256
#pragma unroll
    for (int it = 0; it < 4; ++it) {
        int flat = it * 256 + tid;
        int r  = flat >> 4;
        int c4 = (flat & 15) * 4;
        float4 f = *reinterpret_cast<const float4*>(
            V + (size_t)(kv0 + r) * 256 + v0 + c4);
        T[c4 + 0][r] = f2bf(f.x);
        T[c4 + 1][r] = f2bf(f.y);
        T[c4 + 2][r] = f2bf(f.z);
        T[c4 + 3][r] = f2bf(f.w);
    }
    __syncthreads();
#pragma unroll
    for (int it = 0; it < 2; ++it) {
        int flat = it * 256 + tid;
        int r  = flat >> 3;
        int c8 = (flat & 7) * 8;
        short8 v8 = *reinterpret_cast<const short8*>(&T[r][c8]);
        *reinterpret_cast<short8*>(Vt + (size_t)(v0 + r) * 8192 + kv0 + c8) = v8;
    }
    // ---- K conversion slice: 512 chunks-of-8 per block ----
    const int bid = blockIdx.x + 128 * blockIdx.y;   // 0..511
#pragma unroll
    for (int it = 0; it < 2; ++it) {
        int i = bid * 512 + it * 256 + tid;          // 0..262143
        const float4* p = reinterpret_cast<const float4*>(K) + (size_t)i * 2;
        float4 a = p[0], b = p[1];
        S8u r;
        r.u[0] = f2bf(a.x); r.u[1] = f2bf(a.y);
        r.u[2] = f2bf(a.z); r.u[3] = f2bf(a.w);
        r.u[4] = f2bf(b.x); r.u[5] = f2bf(b.y);
        r.u[6] = f2bf(b.z); r.u[7] = f2bf(b.w);
        *reinterpret_cast<short8*>(Kb + (size_t)i * 8) = r.v;
    }
}

// ---------------- main attention kernel ----------------

#define MFMA_B16 __builtin_amdgcn_mfma_f32_32x32x16_bf16

__global__ __launch_bounds__(256, 2)
void attn_kernel(const float* __restrict__ Qf,            // [8192][256] fp32
                 const unsigned short* __restrict__ Kb,   // [8192][256] bf16
                 const unsigned short* __restrict__ VtG,  // [256][8192] bf16
                 __half* __restrict__ Opart,              // [NG][8192][256]
                 float* __restrict__ Ml,                  // [NG][8192][2]
                 int kv_span, int gshift) {
    // [buf][ K 16KB ] and [buf][ Vt 16KB ]  (tile = 32 kv)
    __shared__ __align__(16) unsigned char kbuf[2][16384];
    __shared__ __align__(16) unsigned char vbuf[2][16384];

    const int tid  = threadIdx.x;
    const int lane = tid & 63;
    const int w    = tid >> 6;     // 0..3
    const int l31  = lane & 31;
    const int h    = lane >> 5;    // 0/1

    const int ngm1 = (1 << gshift) - 1;
    const int id   = blockIdx.x + 64 * blockIdx.y;
    const int g    = id & ngm1;          // XCD-affine
    const int qblk = id >> gshift;       // 0..63
    const int kv_begin = g * kv_span;
    const int tiles = kv_span >> 5;
    const int q0 = qblk * 128 + w * 32;

    // Q as B-fragments, fp32 -> bf16 with scale log2(e)/16 (exp2 domain)
    const float qs = 0.09016844005556021f;
    short8 qf[16];
    {
        const float* qp = Qf + (size_t)(q0 + l31) * 256 + h * 8;
#pragma unroll
        for (int ds = 0; ds < 16; ++ds) {
            float4 f0 = *reinterpret_cast<const float4*>(qp + ds * 16);
            float4 f1 = *reinterpret_cast<const float4*>(qp + ds * 16 + 4);
            uint4 uu;
            uu.x = cvtpk_bf16(f0.x * qs, f0.y * qs);
            uu.y = cvtpk_bf16(f0.z * qs, f0.w * qs);
            uu.z = cvtpk_bf16(f1.x * qs, f1.y * qs);
            uu.w = cvtpk_bf16(f1.z * qs, f1.w * qs);
            qf[ds] = __builtin_bit_cast(short8, uu);
        }
    }

    floatx16 o[8];
#pragma unroll
    for (int vt = 0; vt < 8; ++vt)
#pragma unroll
        for (int r = 0; r < 16; ++r) o[vt][r] = 0.f;
    float m_run = -1e30f, l_run = 0.f;

    // staging offsets (verified R9 maps): 16B-chunk j = i*256 + tid
    int offk[4], offv[4];
#pragma unroll
    for (int i = 0; i < 4; ++i) {
        int j  = i * 256 + tid;
        int rk = j >> 5, ck = (j & 31) ^ (rk & 7);
        offk[i] = rk * 256 + ck * 8;
        int rv = j >> 2, cv = (j & 3) ^ ((rv >> 1) & 3);
        offv[i] = rv * 8192 + cv * 8;
    }

    auto STAGEK = [&](int kv0, int bufsel) {
        const unsigned short* ks = Kb + (size_t)kv0 * 256;
#pragma unroll
        for (int i = 0; i < 4; ++i)
            gload16(ks + offk[i], &kbuf[bufsel][(i * 256 + w * 64) * 16]);
    };
    auto STAGEV = [&](int kv0, int bufsel) {
        const unsigned short* vs = VtG + kv0;
#pragma unroll
        for (int i = 0; i < 4; ++i)
            gload16(vs + offv[i], &vbuf[bufsel][(i * 256 + w * 64) * 16]);
    };

    // ---- prologue: K(0); V(0) into BOTH buffers (body-0 dummy PV reads
    // vbuf[1] with pa=0 -> real finite data, contributes exactly 0) ----
    STAGEK(kv_begin, 0);
    STAGEV(kv_begin, 0);
    STAGEV(kv_begin, 1);
    __syncthreads();

    const int swz  = l31 & 7;          // K-read swizzle
    const int vswz = (l31 >> 1) & 3;   // V-read swizzle

    auto buildPA = [&](const floatx16& sv, int rbase) -> short8 {
        unsigned cpk0 = cvtpk_bf16(sv[rbase + 0], sv[rbase + 1]);
        unsigned cpk1 = cvtpk_bf16(sv[rbase + 2], sv[rbase + 3]);
        unsigned cpk2 = cvtpk_bf16(sv[rbase + 4], sv[rbase + 5]);
        unsigned cpk3 = cvtpk_bf16(sv[rbase + 6], sv[rbase + 7]);
        uint4 uu;
#if __has_builtin(__builtin_amdgcn_permlane32_swap)
        auto r02 = __builtin_amdgcn_permlane32_swap((int)cpk0, (int)cpk2, false, false);
        auto r13 = __builtin_amdgcn_permlane32_swap((int)cpk1, (int)cpk3, false, false);
        uu.x = (unsigned)r02[0]; uu.y = (unsigned)r13[0];
        uu.z = (unsigned)r02[1]; uu.w = (unsigned)r13[1];
#else
        unsigned send0 = h ? cpk0 : cpk2;
        unsigned send1 = h ? cpk1 : cpk3;
        unsigned r0 = (unsigned)__shfl_xor((int)send0, 32);
        unsigned r1 = (unsigned)__shfl_xor((int)send1, 32);
        uu.x = h ? r0 : cpk0;
        uu.y = h ? r1 : cpk1;
        uu.z = h ? cpk2 : r0;
        uu.w = h ? cpk3 : r1;
#endif
        return __builtin_bit_cast(short8, uu);
    };

    // P(t-1) carried across bodies (zero for body 0 -> dummy PV adds 0)
    short8 pa0 = __builtin_bit_cast(short8, uint4{0u, 0u, 0u, 0u});
    short8 pa1 = pa0;

    for (int t = 0; t < tiles; ++t) {
        const int cur = t & 1;
        const int nxt = cur ^ 1;
        const int tn  = (t + 1 < tiles) ? t + 1 : t;   // dummy restage on last

        // ---- issue staging: K(t+1) and V(t); land by end of body ----
        STAGEK(kv_begin + tn * 32, nxt);
        STAGEV(kv_begin + t * 32, cur);

        const unsigned char* kl  = kbuf[cur];   // K(t)
        const unsigned char* vlp = vbuf[nxt];   // V(t-1)  ((t-1)&1 == nxt)

        // ---- QKT(t) interleaved 1:1 with PV(t-1): independent MFMAs ----
        floatx16 s;
#pragma unroll
        for (int r = 0; r < 16; ++r) s[r] = 0.f;
        __builtin_amdgcn_s_setprio(1);
#pragma unroll
        for (int ds = 0; ds < 16; ++ds) {
            int c0 = (ds * 2 + h) ^ swz;
            short8 a0 = *reinterpret_cast<const short8*>(
                kl + (size_t)l31 * 512 + c0 * 16);
            s = MFMA_B16(a0, qf[ds], s, 0, 0, 0);
            const int kk = ds >> 3, vt = ds & 7;
            int cvs = (kk * 2 + h) ^ vswz;
            short8 b = *reinterpret_cast<const short8*>(
                vlp + (size_t)(vt * 32 + l31) * 64 + cvs * 16);
            o[vt] = MFMA_B16(kk ? pa1 : pa0, b, o[vt], 0, 0, 0);
        }
        __builtin_amdgcn_s_setprio(0);

        // ---- online softmax on tile t (exp2 domain, tree reductions) ----
        {
            float t4[4];
#pragma unroll
            for (int i = 0; i < 4; ++i)
                t4[i] = fmaxf(fmaxf(s[i], s[i + 4]),
                              fmaxf(s[i + 8], s[i + 12]));
            float mt = fmaxf(fmaxf(t4[0], t4[1]), fmaxf(t4[2], t4[3]));
            mt = fmaxf(mt, __shfl_xor(mt, 32));
            if (__any(mt > m_run + 11.5f)) {      // defer-max (log2 units)
                float mnew = fmaxf(m_run, mt);
                float al = EXP2F(m_run - mnew);
                m_run = mnew;
                l_run *= al;
#pragma unroll
                for (int reg = 0; reg < 16; ++reg) {
                    int srcl = ((reg & 3) + 8 * (reg >> 2)) + 4 * h;
                    float alr = __shfl(al, srcl);
#pragma unroll
                    for (int vt = 0; vt < 8; ++vt) o[vt][reg] *= alr;
                }
            }
#pragma unroll
            for (int r = 0; r < 16; ++r) s[r] = EXP2F(s[r] - m_run);
            float u[4];
#pragma unroll
            for (int i = 0; i < 4; ++i)
                u[i] = (s[i] + s[i + 4]) + (s[i + 8] + s[i + 12]);
            float lt = (u[0] + u[1]) + (u[2] + u[3]);
            lt += __shfl_xor(lt, 32);
            l_run += lt;
        }
        pa0 = buildPA(s, 0);
        pa1 = buildPA(s, 8);

        // ---- drain this body's staging; rotate ----
        __syncthreads();
    }

    // ---- epilogue PV for the last tile ----
    {
        const unsigned char* vlq = vbuf[(tiles - 1) & 1];
        __builtin_amdgcn_s_setprio(1);
#pragma unroll
        for (int kk = 0; kk < 2; ++kk) {
            int cvs = (kk * 2 + h) ^ vswz;
#pragma unroll
            for (int vt = 0; vt < 8; ++vt) {
                short8 b = *reinterpret_cast<const short8*>(
                    vlq + (size_t)(vt * 32 + l31) * 64 + cvs * 16);
                o[vt] = MFMA_B16(kk ? pa1 : pa0, b, o[vt], 0, 0, 0);
            }
        }
        __builtin_amdgcn_s_setprio(0);
    }

    // ---- epilogue: normalized fp16 partial + (m,l) fp32 ----
    const size_t gq = (size_t)g * 8192;
    float linv = 1.0f / l_run;
#pragma unroll
    for (int reg = 0; reg < 16; ++reg) {
        int row = (reg & 3) + 8 * (reg >> 2) + 4 * h;
        float li = __shfl(linv, row);
#pragma unroll
        for (int vt = 0; vt < 8; ++vt)
            Opart[(gq + q0 + row) * 256 + vt * 32 + l31] =
                __float2half_rn(o[vt][reg] * li);
    }
    if (h == 0) {
        size_t idx = (gq + q0 + l31) * 2;
        Ml[idx]     = m_run;   // log2 domain
        Ml[idx + 1] = l_run;
    }
}

// ---------------- merge kernel (half2-vectorized) ----------------

__global__ void merge_kernel(const __half* __restrict__ Opart,
                             const float* __restrict__ Ml,
                             float* __restrict__ out, int ngroups) {
    const int row = blockIdx.x;
    const int c2  = threadIdx.x;           // 0..127, col pair
    float m = -1e30f;
    for (int g = 0; g < ngroups; ++g)
        m = fmaxf(m, Ml[((size_t)g * 8192 + row) * 2]);
    float den = 0.f, ax = 0.f, ay = 0.f;
    for (int g = 0; g < ngroups; ++g) {
        float wg = EXP2F(Ml[((size_t)g * 8192 + row) * 2] - m) *
                   Ml[((size_t)g * 8192 + row) * 2 + 1];
        den += wg;
        __half2 h2 = *reinterpret_cast<const __half2*>(
            &Opart[((size_t)g * 8192 + row) * 256 + c2 * 2]);
        float2 f = __half22float2(h2);
        ax += wg * f.x;
        ay += wg * f.y;
    }
    float dinv = 1.0f / den;
    float2 r; r.x = ax * dinv; r.y = ay * dinv;
    *reinterpret_cast<float2*>(&out[(size_t)row * 256 + c2 * 2]) = r;
}

// ---------------- launcher ----------------

extern "C" void kernel_launch(void* const* d_in, const int* in_sizes, int n_in,
                              void* d_out, int out_size, void* d_ws, size_t ws_size,
                              hipStream_t stream) {
    const float* Q = (const float*)d_in[0];
    const float* K = (const float*)d_in[1];
    const float* V = (const float*)d_in[2];
    float* out = (float*)d_out;

    unsigned short* Kb = (unsigned short*)d_ws;            // 4 MiB
    unsigned short* Vt = Kb + (size_t)8192 * 256;          // 4 MiB

    const size_t base = (size_t)8192 * 256 * 2 * 2;        // 8 MiB
    const size_t osz  = (size_t)8192 * 256 * 2;            // 4 MiB/group (fp16)
    const size_t mlsz = (size_t)8192 * 2 * 4;              // 64 KiB/group

    int gshift = 3;
    for (; gshift > 0; --gshift)
        if (base + ((osz + mlsz) << gshift) <= ws_size) break;
    int ng = 1 << gshift;

    __half* Opart = (__half*)((char*)d_ws + base);
    float*  Mlp   = (float*)((char*)d_ws + base + osz * (size_t)ng);

    prep_kernel<<<dim3(128, 4), 256, 0, stream>>>(K, V, Kb, Vt);
    attn_kernel<<<dim3(64, ng), 256, 0, stream>>>(Q, Kb, Vt, Opart, Mlp,
                                                  8192 / ng, gshift);
    merge_kernel<<<8192, 128, 0, stream>>>(Opart, Mlp, out, ng);
}